// Round 6
// baseline (499.658 us; speedup 1.0000x reference)
//
#include <hip/hip_runtime.h>

#define T_TOK 8192
#define D_DIM 1024
#define E_NUM 32
#define K_TOP 4
#define CAP 1280
#define I_DIM 512

typedef float f32x4 __attribute__((ext_vector_type(4)));
typedef short s16x8 __attribute__((ext_vector_type(8)));

static __device__ __forceinline__ unsigned short f2bf(float f) {
    unsigned int u = __float_as_uint(f);
    unsigned int r = (u + 0x7fffu + ((u >> 16) & 1u)) >> 16;
    return (unsigned short)r;
}
static __device__ __forceinline__ float bf2f(unsigned short s) {
    return __uint_as_float(((unsigned int)s) << 16);
}

// async 16B global->LDS (dest = wave-uniform base + lane*16)
static __device__ __forceinline__ void gload16(const unsigned short* g, unsigned short* l) {
    __builtin_amdgcn_global_load_lds(
        (const __attribute__((address_space(1))) unsigned int*)g,
        (__attribute__((address_space(3))) unsigned int*)l,
        16, 0, 0);
}

// ---------------- fp32 -> bf16 pre-convert (gate_w, up_w, down_w; x handled by router) ----------------
#define GW_F4 4194304L
__global__ __launch_bounds__(256) void cvt_kernel(
    const float* __restrict__ gw,
    const float* __restrict__ uw, const float* __restrict__ dw,
    unsigned short* __restrict__ gbf,
    unsigned short* __restrict__ ubf, unsigned short* __restrict__ dbf) {
    long i = (long)blockIdx.x * 256 + threadIdx.x;   // float4 index
    const float* src; unsigned short* dst; long off;
    if (i < GW_F4)        { src = gw; dst = gbf; off = i; }
    else if (i < 2*GW_F4) { src = uw; dst = ubf; off = i - GW_F4; }
    else                  { src = dw; dst = dbf; off = i - 2*GW_F4; }
    float4 v = ((const float4*)src)[off];
    ushort4 b;
    b.x = f2bf(v.x); b.y = f2bf(v.y); b.z = f2bf(v.z); b.w = f2bf(v.w);
    ((ushort4*)dst)[off] = b;
}

// ---------------- router: logits = x @ router_w^T (fp32 exact) + x->bf16 side output ----------------
__global__ __launch_bounds__(256) void router_kernel(
    const float* __restrict__ x, const float* __restrict__ rw,
    float* __restrict__ logits, unsigned short* __restrict__ xbf) {
    int t = (blockIdx.x * 256 + threadIdx.x) >> 6;   // one wave per token
    int lane = threadIdx.x & 63;
    const float* xr = x + (size_t)t * D_DIM;
    float xf[16];
#pragma unroll
    for (int j = 0; j < 16; ++j) xf[j] = xr[lane + 64 * j];
    unsigned short* xb = xbf + (size_t)t * D_DIM;
#pragma unroll
    for (int j = 0; j < 16; ++j) xb[lane + 64 * j] = f2bf(xf[j]);
#pragma unroll 1
    for (int e = 0; e < E_NUM; ++e) {
        const float* wr = rw + (size_t)e * D_DIM;
        float acc = 0.f;
#pragma unroll
        for (int j = 0; j < 16; ++j) acc = fmaf(xf[j], wr[lane + 64 * j], acc);
#pragma unroll
        for (int off = 32; off; off >>= 1) acc += __shfl_xor(acc, off);
        if (lane == 0) logits[(size_t)t * E_NUM + e] = acc;
    }
}

// ------------- softmax + top-4 + renorm + slot assignment (thread/token, LDS histogram) -------------
__global__ __launch_bounds__(256) void topk_kernel(
    const float* __restrict__ logits,
    int* __restrict__ counts, int* __restrict__ rowtok,
    int* __restrict__ tokslot, float* __restrict__ tokcoef) {
    __shared__ float lg[256 * 33];
    __shared__ int hist[E_NUM];
    __shared__ int base[E_NUM];
    int tid = threadIdx.x;
    int t0 = blockIdx.x * 256;
    if (tid < E_NUM) hist[tid] = 0;
#pragma unroll
    for (int i = 0; i < E_NUM; ++i) {
        int idx = i * 256 + tid;
        lg[(idx >> 5) * 33 + (idx & 31)] = logits[(size_t)t0 * E_NUM + idx];
    }
    __syncthreads();

    float p[E_NUM];
    float m = -1e30f;
#pragma unroll
    for (int e = 0; e < E_NUM; ++e) { p[e] = lg[tid * 33 + e]; m = fmaxf(m, p[e]); }
#pragma unroll
    for (int e = 0; e < E_NUM; ++e) p[e] = __expf(p[e] - m);

    float wv[K_TOP]; int sel[K_TOP];
#pragma unroll
    for (int k = 0; k < K_TOP; ++k) {
        float best = -1.0f; int bi = 0;
#pragma unroll
        for (int e = 0; e < E_NUM; ++e) if (p[e] > best) { best = p[e]; bi = e; }
        wv[k] = best; sel[k] = bi; p[bi] = -2.0f;
    }

    int lofs[K_TOP];
#pragma unroll
    for (int k = 0; k < K_TOP; ++k) lofs[k] = atomicAdd(&hist[sel[k]], 1);
    __syncthreads();
    if (tid < E_NUM) base[tid] = atomicAdd(&counts[tid], hist[tid]);
    __syncthreads();

    float inv = 1.0f / (wv[0] + wv[1] + wv[2] + wv[3]);
    int t = t0 + tid;
#pragma unroll
    for (int k = 0; k < K_TOP; ++k) {
        int e = sel[k];
        int slot = base[e] + lofs[k];
        if (slot < CAP) {
            rowtok[e * CAP + slot] = t;
            tokslot[t * K_TOP + k] = e * CAP + slot;
        } else {
            tokslot[t * K_TOP + k] = -1;
        }
        tokcoef[t * K_TOP + k] = wv[k] * inv;
    }
}

// ------- gate+up fused GEMM: 256Mx128N, BK=64, 512 thr / 8 waves (4Mx2N), h = silu(g)*u -------
// R4 K-loop body (T2 both-sides swizzle + T4 counted vmcnt + T5 setprio), wrapped in a
// persistent-lite mt loop: grid = exactly 256 blocks = (e, nt, h); block handles mt = h, h+2, ...
// -> zero dispatch tail (1 block/CU, single round) and B-panel stays L2-hot across mt tiles.
__global__ __launch_bounds__(512, 2) void gateup_kernel(
    const unsigned short* __restrict__ xbf,
    const unsigned short* __restrict__ gbf, const unsigned short* __restrict__ ubf,
    const int* __restrict__ counts, const int* __restrict__ rowtok,
    unsigned short* __restrict__ h_ws) {
    int bid = blockIdx.x;                 // 256 blocks; bid&7 == XCD (m09)
    int e = (bid & 7) + 8 * (bid >> 6);   // 4 experts per XCD
    int rem = (bid >> 3) & 7;             // nt*2 + h
    int nt = rem >> 1;                    // [0,4)
    int h = rem & 1;
    int n_e = counts[e]; if (n_e > CAP) n_e = CAP;

    __shared__ unsigned short As[2][256 * 64];   // 64 KB
    __shared__ unsigned short Bg[2][128 * 64];   // 32 KB
    __shared__ unsigned short Bu[2][128 * 64];   // 32 KB
    __shared__ int toks[256];

    int tid = threadIdx.x, lane = tid & 63, wv = tid >> 6;

    int row8 = tid >> 3;                 // [0,64): row within 64-row slab
    // pre-swizzled global source slot: LDS slot (tid&7) receives logical slot (tid&7)^(row&7)
    int c8 = (((tid & 7) ^ (row8 & 7)) * 8);
    int ldst = tid * 8;                  // linear dest short offset within a slab
    const unsigned short* gB[2];
    const unsigned short* uB[2];
#pragma unroll
    for (int j = 0; j < 2; ++j) {
        gB[j] = gbf + ((size_t)e * I_DIM + nt * 128 + j * 64 + row8) * D_DIM + c8;
        uB[j] = ubf + ((size_t)e * I_DIM + nt * 128 + j * 64 + row8) * D_DIM + c8;
    }

    int wm = (wv >> 1) * 64;             // {0,64,128,192}
    int wn = (wv & 1) * 64;              // {0,64}
    int fr = lane & 15;
    int fc = (lane >> 4) * 8;
    int fsw = (fr & 7) << 3;             // read-side XOR (shorts)
    int rq = (lane >> 4) * 4;
    int cq = lane & 15;

    for (int mt = h; mt < 5 && mt * 256 < n_e; mt += 2) {
        __syncthreads();                 // laggards done reading LDS (buf 1, toks) of prev tile
        if (tid < 256) {
            int rr = mt * 256 + tid;
            toks[tid] = (rr < n_e) ? rowtok[e * CAP + rr] : rowtok[e * CAP];
        }
        __syncthreads();

        const unsigned short* aB[4];
#pragma unroll
        for (int j = 0; j < 4; ++j)
            aB[j] = xbf + (size_t)toks[j * 64 + row8] * D_DIM + c8;

        f32x4 accg[4][4] = {};
        f32x4 accu[4][4] = {};

        auto stage = [&](int kt) {
            int q = kt & 1, k2 = kt * 64;
#pragma unroll
            for (int j = 0; j < 4; ++j) gload16(aB[j] + k2, &As[q][j * 4096 + ldst]);
#pragma unroll
            for (int j = 0; j < 2; ++j) {
                gload16(gB[j] + k2, &Bg[q][j * 4096 + ldst]);
                gload16(uB[j] + k2, &Bu[q][j * 4096 + ldst]);
            }
        };
        auto compute = [&](int p) {
#pragma unroll
            for (int kk = 0; kk < 2; ++kk) {
                s16x8 af[4], bgf[4], buf_[4];
#pragma unroll
                for (int mi = 0; mi < 4; ++mi)
                    af[mi] = *(const s16x8*)&As[p][(wm + mi * 16 + fr) * 64 + ((kk * 32 + fc) ^ fsw)];
#pragma unroll
                for (int ni = 0; ni < 4; ++ni) {
                    bgf[ni]  = *(const s16x8*)&Bg[p][(wn + ni * 16 + fr) * 64 + ((kk * 32 + fc) ^ fsw)];
                    buf_[ni] = *(const s16x8*)&Bu[p][(wn + ni * 16 + fr) * 64 + ((kk * 32 + fc) ^ fsw)];
                }
#pragma unroll
                for (int mi = 0; mi < 4; ++mi)
#pragma unroll
                    for (int ni = 0; ni < 4; ++ni) {
                        accg[mi][ni] = __builtin_amdgcn_mfma_f32_16x16x32_bf16(af[mi], bgf[ni],  accg[mi][ni], 0, 0, 0);
                        accu[mi][ni] = __builtin_amdgcn_mfma_f32_16x16x32_bf16(af[mi], buf_[ni], accu[mi][ni], 0, 0, 0);
                    }
            }
        };

        stage(0); stage(1);                  // 16 loads in flight
        for (int kt = 0; kt < 15; ++kt) {    // tiles 0..14; tile 15 peeled
            int p = kt & 1;
            asm volatile("s_waitcnt vmcnt(8)" ::: "memory");   // tile kt landed (kt+1 in flight)
            asm volatile("s_barrier" ::: "memory");            // all waves' tile-kt loads landed
            __builtin_amdgcn_s_setprio(1);
            compute(p);
            __builtin_amdgcn_s_setprio(0);
            asm volatile("s_barrier" ::: "memory");            // all waves done reading parity p
            if (kt < 14) stage(kt + 2);                        // overwrite parity p
        }
        asm volatile("s_waitcnt vmcnt(0)" ::: "memory");
        asm volatile("s_barrier" ::: "memory");
        __builtin_amdgcn_s_setprio(1);
        compute(1);                          // tile 15
        __builtin_amdgcn_s_setprio(0);

#pragma unroll
        for (int mi = 0; mi < 4; ++mi)
#pragma unroll
            for (int ni = 0; ni < 4; ++ni)
#pragma unroll
                for (int rr = 0; rr < 4; ++rr) {
                    int grow = mt * 256 + wm + mi * 16 + rq + rr;
                    if (grow < n_e) {
                        float g = accg[mi][ni][rr];
                        float hv = g / (1.0f + __expf(-g)) * accu[mi][ni][rr];
                        int icol = nt * 128 + wn + ni * 16 + cq;
                        h_ws[((size_t)e * CAP + grow) * I_DIM + icol] = f2bf(hv);
                    }
                }
    }
}

// ---------- down GEMM: 256Mx256N, BK=64, 512 thr / 8 waves (2Mx4N), persistent-lite -> y_ws bf16 ----------
__global__ __launch_bounds__(512, 2) void down_kernel(
    const unsigned short* __restrict__ h_ws, const unsigned short* __restrict__ dbf,
    const int* __restrict__ counts, unsigned short* __restrict__ y_ws) {
    int bid = blockIdx.x;                 // 256 blocks; bid&7 == XCD
    int e = (bid & 7) + 8 * (bid >> 6);
    int rem = (bid >> 3) & 7;             // nt*2 + h
    int nt = rem >> 1;                    // [0,4)
    int h = rem & 1;
    int n_e = counts[e]; if (n_e > CAP) n_e = CAP;

    __shared__ unsigned short As[2][256 * 64];   // 64 KB
    __shared__ unsigned short Bd[2][256 * 64];   // 64 KB

    int tid = threadIdx.x, lane = tid & 63, wv = tid >> 6;

    int row8 = tid >> 3;
    int c8 = (((tid & 7) ^ (row8 & 7)) * 8);
    int ldst = tid * 8;
    const unsigned short* bB[4];
#pragma unroll
    for (int j = 0; j < 4; ++j)
        bB[j] = dbf + ((size_t)e * D_DIM + nt * 256 + j * 64 + row8) * I_DIM + c8;

    int wm = (wv >> 2) * 128;            // {0,128}
    int wn = (wv & 3) * 64;              // {0,64,128,192}
    int fr = lane & 15;
    int fc = (lane >> 4) * 8;
    int fsw = (fr & 7) << 3;
    int rq = (lane >> 4) * 4;
    int cq = lane & 15;

    for (int mt = h; mt < 5 && mt * 256 < n_e; mt += 2) {
        __syncthreads();                 // laggards done reading LDS of prev tile

        const unsigned short* aB[4];
#pragma unroll
        for (int j = 0; j < 4; ++j)
            aB[j] = h_ws + ((size_t)e * CAP + mt * 256 + j * 64 + row8) * I_DIM + c8;

        f32x4 acc[8][4] = {};

        auto stage = [&](int kt) {
            int q = kt & 1, k2 = kt * 64;
#pragma unroll
            for (int j = 0; j < 4; ++j) {
                gload16(aB[j] + k2, &As[q][j * 4096 + ldst]);
                gload16(bB[j] + k2, &Bd[q][j * 4096 + ldst]);
            }
        };
        auto compute = [&](int p) {
#pragma unroll
            for (int kk = 0; kk < 2; ++kk) {
                s16x8 af[8], bf[4];
#pragma unroll
                for (int mi = 0; mi < 8; ++mi)
                    af[mi] = *(const s16x8*)&As[p][(wm + mi * 16 + fr) * 64 + ((kk * 32 + fc) ^ fsw)];
#pragma unroll
                for (int ni = 0; ni < 4; ++ni)
                    bf[ni] = *(const s16x8*)&Bd[p][(wn + ni * 16 + fr) * 64 + ((kk * 32 + fc) ^ fsw)];
#pragma unroll
                for (int mi = 0; mi < 8; ++mi)
#pragma unroll
                    for (int ni = 0; ni < 4; ++ni)
                        acc[mi][ni] = __builtin_amdgcn_mfma_f32_16x16x32_bf16(af[mi], bf[ni], acc[mi][ni], 0, 0, 0);
            }
        };

        stage(0); stage(1);
        for (int kt = 0; kt < 7; ++kt) {     // tiles 0..6; tile 7 peeled
            int p = kt & 1;
            asm volatile("s_waitcnt vmcnt(8)" ::: "memory");
            asm volatile("s_barrier" ::: "memory");
            __builtin_amdgcn_s_setprio(1);
            compute(p);
            __builtin_amdgcn_s_setprio(0);
            asm volatile("s_barrier" ::: "memory");
            if (kt < 6) stage(kt + 2);
        }
        asm volatile("s_waitcnt vmcnt(0)" ::: "memory");
        asm volatile("s_barrier" ::: "memory");
        __builtin_amdgcn_s_setprio(1);
        compute(1);                          // tile 7
        __builtin_amdgcn_s_setprio(0);

#pragma unroll
        for (int mi = 0; mi < 8; ++mi)
#pragma unroll
            for (int ni = 0; ni < 4; ++ni)
#pragma unroll
                for (int rr = 0; rr < 4; ++rr) {
                    int grow = mt * 256 + wm + mi * 16 + rq + rr;
                    if (grow < n_e) {
                        int dcol = nt * 256 + wn + ni * 16 + cq;
                        y_ws[((size_t)e * CAP + grow) * D_DIM + dcol] = f2bf(acc[mi][ni][rr]);
                    }
                }
    }
}

// ---------------- combine: out[t] = sum_k coef_k * y_ws[slot_k]  (one wave/token) ----------------
__global__ __launch_bounds__(256) void combine_kernel(
    const unsigned short* __restrict__ y_ws,
    const int* __restrict__ tokslot, const float* __restrict__ tokcoef,
    float* __restrict__ out) {
    int t = (blockIdx.x * 256 + threadIdx.x) >> 6;
    int lane = threadIdx.x & 63;
    float acc[16] = {};
#pragma unroll
    for (int k = 0; k < K_TOP; ++k) {
        int slot = tokslot[t * K_TOP + k];           // wave-uniform
        if (slot >= 0) {
            float c = tokcoef[t * K_TOP + k];
            const unsigned short* row = y_ws + (size_t)slot * D_DIM + lane * 16;
            s16x8 v0 = *(const s16x8*)row;
            s16x8 v1 = *(const s16x8*)(row + 8);
#pragma unroll
            for (int j = 0; j < 8; ++j) acc[j]     = fmaf(c, bf2f((unsigned short)v0[j]), acc[j]);
#pragma unroll
            for (int j = 0; j < 8; ++j) acc[8 + j] = fmaf(c, bf2f((unsigned short)v1[j]), acc[8 + j]);
        }
    }
    float* o = out + (size_t)t * D_DIM + lane * 16;
#pragma unroll
    for (int j = 0; j < 4; ++j)
        ((float4*)o)[j] = make_float4(acc[4 * j], acc[4 * j + 1], acc[4 * j + 2], acc[4 * j + 3]);
}

extern "C" void kernel_launch(void* const* d_in, const int* in_sizes, int n_in,
                              void* d_out, int out_size, void* d_ws, size_t ws_size,
                              hipStream_t stream) {
    const float* x  = (const float*)d_in[0];
    const float* rw = (const float*)d_in[1];
    const float* gw = (const float*)d_in[2];
    const float* uw = (const float*)d_in[3];
    const float* dw = (const float*)d_in[4];
    float* out = (float*)d_out;
    float* logits = out + (size_t)T_TOK * D_DIM;

    char* ws = (char*)d_ws;
    size_t off = 0;
    // region A (84 MB): xbf|gbf|ubf — dead after gateup; aliased by y_ws afterwards
    unsigned short* xbf = (unsigned short*)(ws + off); off += (size_t)T_TOK * D_DIM * 2;          // 16.78 MB
    unsigned short* gbf = (unsigned short*)(ws + off); off += (size_t)E_NUM * I_DIM * D_DIM * 2;  // 33.55 MB
    unsigned short* ubf = (unsigned short*)(ws + off); off += (size_t)E_NUM * I_DIM * D_DIM * 2;  // 33.55 MB
    unsigned short* y_ws = xbf;  // [E, CAP, D] bf16 = 83.89 MB, exactly region A
    unsigned short* dbf = (unsigned short*)(ws + off); off += (size_t)E_NUM * D_DIM * I_DIM * 2;  // 33.55 MB
    unsigned short* h_ws = (unsigned short*)(ws + off); off += (size_t)E_NUM * CAP * I_DIM * 2;   // 41.94 MB
    int* counts = (int*)(ws + off); off += 256;
    int* rowtok = (int*)(ws + off); off += (size_t)E_NUM * CAP * 4;
    int* tokslot = (int*)(ws + off); off += (size_t)T_TOK * K_TOP * 4;
    float* tokcoef = (float*)(ws + off); off += (size_t)T_TOK * K_TOP * 4;

    hipMemsetAsync(counts, 0, E_NUM * 4, stream);

    cvt_kernel<<<(int)((3 * GW_F4) / 256), 256, 0, stream>>>(gw, uw, dw, gbf, ubf, dbf);
    router_kernel<<<T_TOK / 4, 256, 0, stream>>>(x, rw, logits, xbf);
    topk_kernel<<<T_TOK / 256, 256, 0, stream>>>(logits, counts, rowtok, tokslot, tokcoef);
    gateup_kernel<<<E_NUM * 8, 512, 0, stream>>>(xbf, gbf, ubf, counts, rowtok, h_ws);
    down_kernel<<<E_NUM * 8, 512, 0, stream>>>(h_ws, dbf, counts, y_ws);
    combine_kernel<<<T_TOK / 4, 256, 0, stream>>>(y_ws, tokslot, tokcoef, out);
}

// Round 8
// 454.800 us; speedup vs baseline: 1.0986x; 1.0986x over previous
//
#include <hip/hip_runtime.h>

#define T_TOK 8192
#define D_DIM 1024
#define E_NUM 32
#define K_TOP 4
#define CAP 1280
#define I_DIM 512

typedef float f32x4 __attribute__((ext_vector_type(4)));
typedef short s16x8 __attribute__((ext_vector_type(8)));

static __device__ __forceinline__ unsigned short f2bf(float f) {
    unsigned int u = __float_as_uint(f);
    unsigned int r = (u + 0x7fffu + ((u >> 16) & 1u)) >> 16;
    return (unsigned short)r;
}
static __device__ __forceinline__ float bf2f(unsigned short s) {
    return __uint_as_float(((unsigned int)s) << 16);
}

// async 16B global->LDS (dest = wave-uniform base + lane*16)
static __device__ __forceinline__ void gload16(const unsigned short* g, unsigned short* l) {
    __builtin_amdgcn_global_load_lds(
        (const __attribute__((address_space(1))) unsigned int*)g,
        (__attribute__((address_space(3))) unsigned int*)l,
        16, 0, 0);
}

// ---------------- fp32 -> bf16 pre-convert (gate_w, up_w, down_w; x handled by router) ----------------
#define GW_F4 4194304L
__global__ __launch_bounds__(256) void cvt_kernel(
    const float* __restrict__ gw,
    const float* __restrict__ uw, const float* __restrict__ dw,
    unsigned short* __restrict__ gbf,
    unsigned short* __restrict__ ubf, unsigned short* __restrict__ dbf) {
    long i = (long)blockIdx.x * 256 + threadIdx.x;   // float4 index
    const float* src; unsigned short* dst; long off;
    if (i < GW_F4)        { src = gw; dst = gbf; off = i; }
    else if (i < 2*GW_F4) { src = uw; dst = ubf; off = i - GW_F4; }
    else                  { src = dw; dst = dbf; off = i - 2*GW_F4; }
    float4 v = ((const float4*)src)[off];
    ushort4 b;
    b.x = f2bf(v.x); b.y = f2bf(v.y); b.z = f2bf(v.z); b.w = f2bf(v.w);
    ((ushort4*)dst)[off] = b;
}

// ---------------- router: logits = x @ router_w^T (fp32 exact) + x->bf16 side output ----------------
__global__ __launch_bounds__(256) void router_kernel(
    const float* __restrict__ x, const float* __restrict__ rw,
    float* __restrict__ logits, unsigned short* __restrict__ xbf) {
    int t = (blockIdx.x * 256 + threadIdx.x) >> 6;   // one wave per token
    int lane = threadIdx.x & 63;
    const float* xr = x + (size_t)t * D_DIM;
    float xf[16];
#pragma unroll
    for (int j = 0; j < 16; ++j) xf[j] = xr[lane + 64 * j];
    unsigned short* xb = xbf + (size_t)t * D_DIM;
#pragma unroll
    for (int j = 0; j < 16; ++j) xb[lane + 64 * j] = f2bf(xf[j]);
#pragma unroll 1
    for (int e = 0; e < E_NUM; ++e) {
        const float* wr = rw + (size_t)e * D_DIM;
        float acc = 0.f;
#pragma unroll
        for (int j = 0; j < 16; ++j) acc = fmaf(xf[j], wr[lane + 64 * j], acc);
#pragma unroll
        for (int off = 32; off; off >>= 1) acc += __shfl_xor(acc, off);
        if (lane == 0) logits[(size_t)t * E_NUM + e] = acc;
    }
}

// ------------- softmax + top-4 + renorm + slot assignment (thread/token, LDS histogram) -------------
__global__ __launch_bounds__(256) void topk_kernel(
    const float* __restrict__ logits,
    int* __restrict__ counts, int* __restrict__ rowtok,
    int* __restrict__ tokslot, float* __restrict__ tokcoef) {
    __shared__ float lg[256 * 33];
    __shared__ int hist[E_NUM];
    __shared__ int base[E_NUM];
    int tid = threadIdx.x;
    int t0 = blockIdx.x * 256;
    if (tid < E_NUM) hist[tid] = 0;
#pragma unroll
    for (int i = 0; i < E_NUM; ++i) {
        int idx = i * 256 + tid;
        lg[(idx >> 5) * 33 + (idx & 31)] = logits[(size_t)t0 * E_NUM + idx];
    }
    __syncthreads();

    float p[E_NUM];
    float m = -1e30f;
#pragma unroll
    for (int e = 0; e < E_NUM; ++e) { p[e] = lg[tid * 33 + e]; m = fmaxf(m, p[e]); }
#pragma unroll
    for (int e = 0; e < E_NUM; ++e) p[e] = __expf(p[e] - m);

    float wv[K_TOP]; int sel[K_TOP];
#pragma unroll
    for (int k = 0; k < K_TOP; ++k) {
        float best = -1.0f; int bi = 0;
#pragma unroll
        for (int e = 0; e < E_NUM; ++e) if (p[e] > best) { best = p[e]; bi = e; }
        wv[k] = best; sel[k] = bi; p[bi] = -2.0f;
    }

    int lofs[K_TOP];
#pragma unroll
    for (int k = 0; k < K_TOP; ++k) lofs[k] = atomicAdd(&hist[sel[k]], 1);
    __syncthreads();
    if (tid < E_NUM) base[tid] = atomicAdd(&counts[tid], hist[tid]);
    __syncthreads();

    float inv = 1.0f / (wv[0] + wv[1] + wv[2] + wv[3]);
    int t = t0 + tid;
#pragma unroll
    for (int k = 0; k < K_TOP; ++k) {
        int e = sel[k];
        int slot = base[e] + lofs[k];
        if (slot < CAP) {
            rowtok[e * CAP + slot] = t;
            tokslot[t * K_TOP + k] = e * CAP + slot;
        } else {
            tokslot[t * K_TOP + k] = -1;
        }
        tokcoef[t * K_TOP + k] = wv[k] * inv;
    }
}

// ------- gate+up fused GEMM: 128Mx64N, BK=64, 256 thr / 4 waves (2Mx2N), wave 64x32, h = silu(g)*u -------
// R4's verified counted-vmcnt double-barrier schedule at QUARTER block size: 64 KB LDS +
// ~180 unified regs -> TWO independent blocks per CU. When one block sits in its vmcnt/
// barrier drain, the other block's waves keep the MFMA pipe fed (m97/m114 mechanism).
// Grid = 2560 = exactly 5 full rounds at 2 blocks/CU (no tail).
__global__ __launch_bounds__(256, 2) void gateup_kernel(
    const unsigned short* __restrict__ xbf,
    const unsigned short* __restrict__ gbf, const unsigned short* __restrict__ ubf,
    const int* __restrict__ counts, const int* __restrict__ rowtok,
    unsigned short* __restrict__ h_ws) {
    int bid = blockIdx.x;
    int xcd = bid & 7;
    int slot = bid >> 3;                 // [0,320)
    int e = xcd + 8 * (slot / 80);       // 4 experts per XCD
    int r = slot % 80;
    int mt = r >> 3;                     // [0,10)
    int nt = r & 7;                      // [0,8)
    int n_e = counts[e]; if (n_e > CAP) n_e = CAP;
    if (mt * 128 >= n_e) return;

    __shared__ unsigned short As[2][128 * 64];   // 32 KB
    __shared__ unsigned short Bg[2][64 * 64];    // 16 KB
    __shared__ unsigned short Bu[2][64 * 64];    // 16 KB
    __shared__ int toks[128];

    int tid = threadIdx.x, lane = tid & 63, wv = tid >> 6;
    if (tid < 128) {
        int rr = mt * 128 + tid;
        toks[tid] = (rr < n_e) ? rowtok[e * CAP + rr] : rowtok[e * CAP];
    }
    __syncthreads();

    int rowi = tid >> 3;                 // [0,32): row within a 32-row slab
    // pre-swizzled global source slot: LDS slot (tid&7) receives logical slot (tid&7)^(row&7)
    int c8 = (((tid & 7) ^ (rowi & 7)) * 8);
    int ldst = tid * 8;                  // linear dest short offset within a 2048-short slab
    const unsigned short* aB[4];
#pragma unroll
    for (int j = 0; j < 4; ++j)
        aB[j] = xbf + (size_t)toks[j * 32 + rowi] * D_DIM + c8;
    const unsigned short* gB[2];
    const unsigned short* uB[2];
#pragma unroll
    for (int j = 0; j < 2; ++j) {
        gB[j] = gbf + ((size_t)e * I_DIM + nt * 64 + j * 32 + rowi) * D_DIM + c8;
        uB[j] = ubf + ((size_t)e * I_DIM + nt * 64 + j * 32 + rowi) * D_DIM + c8;
    }

    int wm = (wv >> 1) * 64;             // {0,64}
    int wn = (wv & 1) * 32;              // {0,32}
    int fr = lane & 15;
    int fc = (lane >> 4) * 8;
    int fsw = (fr & 7) << 3;             // read-side XOR (shorts)
    int rq = (lane >> 4) * 4;
    int cq = lane & 15;

    f32x4 accg[4][2] = {};
    f32x4 accu[4][2] = {};

    auto stage = [&](int kt) {
        int q = kt & 1, k2 = kt * 64;
#pragma unroll
        for (int j = 0; j < 4; ++j) gload16(aB[j] + k2, &As[q][j * 2048 + ldst]);
#pragma unroll
        for (int j = 0; j < 2; ++j) {
            gload16(gB[j] + k2, &Bg[q][j * 2048 + ldst]);
            gload16(uB[j] + k2, &Bu[q][j * 2048 + ldst]);
        }
    };
    auto compute = [&](int p) {
#pragma unroll
        for (int kk = 0; kk < 2; ++kk) {
            s16x8 af[4], bgf[2], buf_[2];
#pragma unroll
            for (int mi = 0; mi < 4; ++mi)
                af[mi] = *(const s16x8*)&As[p][(wm + mi * 16 + fr) * 64 + ((kk * 32 + fc) ^ fsw)];
#pragma unroll
            for (int ni = 0; ni < 2; ++ni) {
                bgf[ni]  = *(const s16x8*)&Bg[p][(wn + ni * 16 + fr) * 64 + ((kk * 32 + fc) ^ fsw)];
                buf_[ni] = *(const s16x8*)&Bu[p][(wn + ni * 16 + fr) * 64 + ((kk * 32 + fc) ^ fsw)];
            }
#pragma unroll
            for (int mi = 0; mi < 4; ++mi)
#pragma unroll
                for (int ni = 0; ni < 2; ++ni) {
                    accg[mi][ni] = __builtin_amdgcn_mfma_f32_16x16x32_bf16(af[mi], bgf[ni],  accg[mi][ni], 0, 0, 0);
                    accu[mi][ni] = __builtin_amdgcn_mfma_f32_16x16x32_bf16(af[mi], buf_[ni], accu[mi][ni], 0, 0, 0);
                }
        }
    };

    stage(0); stage(1);                  // 16 loads in flight (8 per tile)
    for (int kt = 0; kt < 15; ++kt) {    // tiles 0..14; tile 15 peeled
        int p = kt & 1;
        asm volatile("s_waitcnt vmcnt(8)" ::: "memory");   // tile kt landed (kt+1 in flight)
        asm volatile("s_barrier" ::: "memory");            // all waves' tile-kt loads landed
        __builtin_amdgcn_s_setprio(1);
        compute(p);
        __builtin_amdgcn_s_setprio(0);
        asm volatile("s_barrier" ::: "memory");            // all waves done reading parity p
        if (kt < 14) stage(kt + 2);                        // overwrite parity p
    }
    asm volatile("s_waitcnt vmcnt(0)" ::: "memory");
    asm volatile("s_barrier" ::: "memory");
    __builtin_amdgcn_s_setprio(1);
    compute(1);                          // tile 15
    __builtin_amdgcn_s_setprio(0);

#pragma unroll
    for (int mi = 0; mi < 4; ++mi)
#pragma unroll
        for (int ni = 0; ni < 2; ++ni)
#pragma unroll
            for (int rr = 0; rr < 4; ++rr) {
                int grow = mt * 128 + wm + mi * 16 + rq + rr;
                if (grow < n_e) {
                    float g = accg[mi][ni][rr];
                    float hv = g / (1.0f + __expf(-g)) * accu[mi][ni][rr];
                    int icol = nt * 64 + wn + ni * 16 + cq;
                    h_ws[((size_t)e * CAP + grow) * I_DIM + icol] = f2bf(hv);
                }
            }
}

// ---------- down GEMM: 128Mx128N, BK=64, 256 thr / 4 waves (2Mx2N), wave 64x64 -> y_ws bf16 ----------
__global__ __launch_bounds__(256, 2) void down_kernel(
    const unsigned short* __restrict__ h_ws, const unsigned short* __restrict__ dbf,
    const int* __restrict__ counts, unsigned short* __restrict__ y_ws) {
    int bid = blockIdx.x;
    int xcd = bid & 7;
    int slot = bid >> 3;                 // [0,320)
    int e = xcd + 8 * (slot / 80);
    int r = slot % 80;
    int mt = r >> 3;                     // [0,10)
    int nt = r & 7;                      // [0,8)
    int n_e = counts[e]; if (n_e > CAP) n_e = CAP;
    if (mt * 128 >= n_e) return;

    __shared__ unsigned short As[2][128 * 64];   // 32 KB
    __shared__ unsigned short Bd[2][128 * 64];   // 32 KB

    int tid = threadIdx.x, lane = tid & 63, wv = tid >> 6;

    int rowi = tid >> 3;                 // [0,32)
    int c8 = (((tid & 7) ^ (rowi & 7)) * 8);
    int ldst = tid * 8;
    const unsigned short* aB[4];
    const unsigned short* bB[4];
#pragma unroll
    for (int j = 0; j < 4; ++j) {
        aB[j] = h_ws + ((size_t)e * CAP + mt * 128 + j * 32 + rowi) * I_DIM + c8;
        bB[j] = dbf  + ((size_t)e * D_DIM + nt * 128 + j * 32 + rowi) * I_DIM + c8;
    }

    int wm = (wv >> 1) * 64;             // {0,64}
    int wn = (wv & 1) * 64;              // {0,64}
    int fr = lane & 15;
    int fc = (lane >> 4) * 8;
    int fsw = (fr & 7) << 3;
    int rq = (lane >> 4) * 4;
    int cq = lane & 15;

    f32x4 acc[4][4] = {};

    auto stage = [&](int kt) {
        int q = kt & 1, k2 = kt * 64;
#pragma unroll
        for (int j = 0; j < 4; ++j) {
            gload16(aB[j] + k2, &As[q][j * 2048 + ldst]);
            gload16(bB[j] + k2, &Bd[q][j * 2048 + ldst]);
        }
    };
    auto compute = [&](int p) {
#pragma unroll
        for (int kk = 0; kk < 2; ++kk) {
            s16x8 af[4], bf[4];
#pragma unroll
            for (int mi = 0; mi < 4; ++mi)
                af[mi] = *(const s16x8*)&As[p][(wm + mi * 16 + fr) * 64 + ((kk * 32 + fc) ^ fsw)];
#pragma unroll
            for (int ni = 0; ni < 4; ++ni)
                bf[ni] = *(const s16x8*)&Bd[p][(wn + ni * 16 + fr) * 64 + ((kk * 32 + fc) ^ fsw)];
#pragma unroll
            for (int mi = 0; mi < 4; ++mi)
#pragma unroll
                for (int ni = 0; ni < 4; ++ni)
                    acc[mi][ni] = __builtin_amdgcn_mfma_f32_16x16x32_bf16(af[mi], bf[ni], acc[mi][ni], 0, 0, 0);
        }
    };

    stage(0); stage(1);                  // 16 loads in flight (8 per tile)
    for (int kt = 0; kt < 7; ++kt) {     // tiles 0..6; tile 7 peeled
        int p = kt & 1;
        asm volatile("s_waitcnt vmcnt(8)" ::: "memory");
        asm volatile("s_barrier" ::: "memory");
        __builtin_amdgcn_s_setprio(1);
        compute(p);
        __builtin_amdgcn_s_setprio(0);
        asm volatile("s_barrier" ::: "memory");
        if (kt < 6) stage(kt + 2);
    }
    asm volatile("s_waitcnt vmcnt(0)" ::: "memory");
    asm volatile("s_barrier" ::: "memory");
    __builtin_amdgcn_s_setprio(1);
    compute(1);                          // tile 7
    __builtin_amdgcn_s_setprio(0);

#pragma unroll
    for (int mi = 0; mi < 4; ++mi)
#pragma unroll
        for (int ni = 0; ni < 4; ++ni)
#pragma unroll
            for (int rr = 0; rr < 4; ++rr) {
                int grow = mt * 128 + wm + mi * 16 + rq + rr;
                if (grow < n_e) {
                    int dcol = nt * 128 + wn + ni * 16 + cq;
                    y_ws[((size_t)e * CAP + grow) * D_DIM + dcol] = f2bf(acc[mi][ni][rr]);
                }
            }
}

// ---------------- combine: out[t] = sum_k coef_k * y_ws[slot_k]  (one wave/token) ----------------
__global__ __launch_bounds__(256) void combine_kernel(
    const unsigned short* __restrict__ y_ws,
    const int* __restrict__ tokslot, const float* __restrict__ tokcoef,
    float* __restrict__ out) {
    int t = (blockIdx.x * 256 + threadIdx.x) >> 6;
    int lane = threadIdx.x & 63;
    float acc[16] = {};
#pragma unroll
    for (int k = 0; k < K_TOP; ++k) {
        int slot = tokslot[t * K_TOP + k];           // wave-uniform
        if (slot >= 0) {
            float c = tokcoef[t * K_TOP + k];
            const unsigned short* row = y_ws + (size_t)slot * D_DIM + lane * 16;
            s16x8 v0 = *(const s16x8*)row;
            s16x8 v1 = *(const s16x8*)(row + 8);
#pragma unroll
            for (int j = 0; j < 8; ++j) acc[j]     = fmaf(c, bf2f((unsigned short)v0[j]), acc[j]);
#pragma unroll
            for (int j = 0; j < 8; ++j) acc[8 + j] = fmaf(c, bf2f((unsigned short)v1[j]), acc[8 + j]);
        }
    }
    float* o = out + (size_t)t * D_DIM + lane * 16;
#pragma unroll
    for (int j = 0; j < 4; ++j)
        ((float4*)o)[j] = make_float4(acc[4 * j], acc[4 * j + 1], acc[4 * j + 2], acc[4 * j + 3]);
}

extern "C" void kernel_launch(void* const* d_in, const int* in_sizes, int n_in,
                              void* d_out, int out_size, void* d_ws, size_t ws_size,
                              hipStream_t stream) {
    const float* x  = (const float*)d_in[0];
    const float* rw = (const float*)d_in[1];
    const float* gw = (const float*)d_in[2];
    const float* uw = (const float*)d_in[3];
    const float* dw = (const float*)d_in[4];
    float* out = (float*)d_out;
    float* logits = out + (size_t)T_TOK * D_DIM;

    char* ws = (char*)d_ws;
    size_t off = 0;
    // region A (84 MB): xbf|gbf|ubf — dead after gateup; aliased by y_ws afterwards
    unsigned short* xbf = (unsigned short*)(ws + off); off += (size_t)T_TOK * D_DIM * 2;          // 16.78 MB
    unsigned short* gbf = (unsigned short*)(ws + off); off += (size_t)E_NUM * I_DIM * D_DIM * 2;  // 33.55 MB
    unsigned short* ubf = (unsigned short*)(ws + off); off += (size_t)E_NUM * I_DIM * D_DIM * 2;  // 33.55 MB
    unsigned short* y_ws = xbf;  // [E, CAP, D] bf16 = 83.89 MB, exactly region A
    unsigned short* dbf = (unsigned short*)(ws + off); off += (size_t)E_NUM * D_DIM * I_DIM * 2;  // 33.55 MB
    unsigned short* h_ws = (unsigned short*)(ws + off); off += (size_t)E_NUM * CAP * I_DIM * 2;   // 41.94 MB
    int* counts = (int*)(ws + off); off += 256;
    int* rowtok = (int*)(ws + off); off += (size_t)E_NUM * CAP * 4;
    int* tokslot = (int*)(ws + off); off += (size_t)T_TOK * K_TOP * 4;
    float* tokcoef = (float*)(ws + off); off += (size_t)T_TOK * K_TOP * 4;

    hipMemsetAsync(counts, 0, E_NUM * 4, stream);

    cvt_kernel<<<(int)((3 * GW_F4) / 256), 256, 0, stream>>>(gw, uw, dw, gbf, ubf, dbf);
    router_kernel<<<T_TOK / 4, 256, 0, stream>>>(x, rw, logits, xbf);
    topk_kernel<<<T_TOK / 256, 256, 0, stream>>>(logits, counts, rowtok, tokslot, tokcoef);
    gateup_kernel<<<E_NUM * (CAP / 128) * (I_DIM / 64), 256, 0, stream>>>(xbf, gbf, ubf, counts, rowtok, h_ws);
    down_kernel<<<E_NUM * (CAP / 128) * (D_DIM / 128), 256, 0, stream>>>(h_ws, dbf, counts, y_ws);
    combine_kernel<<<T_TOK / 4, 256, 0, stream>>>(y_ws, tokslot, tokcoef, out);
}